// Round 3
// baseline (312.698 us; speedup 1.0000x reference)
//
#include <hip/hip_runtime.h>

// Problem constants (fixed by the reference).
#define BB 32
#define KK 8192
#define EE 128
#define HH 128
#define CH 32                     // chunks per batch -> 1024 blocks
#define TPB (KK / CH)             // 256 tokens per block
#define STRIP 32                  // tokens per LDS strip
#define NSTRIP (TPB / STRIP)      // 8
#define ZSTR 136                  // ml LDS row stride in shorts (272 B)

typedef short bf16x8 __attribute__((ext_vector_type(8)));
typedef float f32x4  __attribute__((ext_vector_type(4)));

static __device__ __forceinline__ unsigned short f2bf(float x) {
    union { float f; unsigned u; } v; v.f = x;
    unsigned u = v.u;
    u += 0x7FFFu + ((u >> 16) & 1u);   // RNE
    return (unsigned short)(u >> 16);
}

static __device__ __forceinline__ bf16x8 cvt8(float4 a, float4 b) {
    bf16x8 r;
    r[0] = (short)f2bf(a.x); r[1] = (short)f2bf(a.y);
    r[2] = (short)f2bf(a.z); r[3] = (short)f2bf(a.w);
    r[4] = (short)f2bf(b.x); r[5] = (short)f2bf(b.y);
    r[6] = (short)f2bf(b.z); r[7] = (short)f2bf(b.w);
    return r;
}

// Async global->LDS, 16 B per lane. LDS dest = wave-uniform base + lane*16.
typedef __attribute__((address_space(1))) void as1_void;
typedef __attribute__((address_space(3))) void as3_void;
static __device__ __forceinline__ void gload_lds16(const void* g, void* l) {
    __builtin_amdgcn_global_load_lds((as1_void*)g, (as3_void*)l, 16, 0, 0);
}

// ---------------------------------------------------------------------------
// Direct MFMA A-fragment gather from fp32 row-major weights (replaces the
// former prepack kernel; identical per-lane element mapping, so the fragment
// data is bit-identical). For fragment (tile, kchunk) of a [F][Kdim] matrix:
// lane (q=lane>>4, l16=lane&15) reads row tile*16+l16, cols kchunk*32+q*8.
// Weights are ~192 KB total -> L2-resident after the first touches; the
// per-block redundant gather (~192 MB aggregate L2 reads) costs ~5 us
// against 34 TB/s L2 and is off the steady-state critical path.
// ---------------------------------------------------------------------------
static __device__ __forceinline__ bf16x8 gather_frag(const float* __restrict__ W,
                                                     int ldw, int tile, int kchunk,
                                                     int l16, int q) {
    const float* src = W + (size_t)(tile * 16 + l16) * ldw + kchunk * 32 + q * 8;
    return cvt8(((const float4*)src)[0], ((const float4*)src)[1]);
}

// ---------------------------------------------------------------------------
// Kernel 1: partial column-max of z @ M2^T; emits z as bf16 (zb) if ws allows.
// zb is stored XOR-SWIZZLED within each 256-B token row:
//   byte_in_row ^= ((token & 7) << 4)
// so that fused_main can stage it LINEARLY via global_load_lds and read
// MFMA B-fragments from LDS bank-conflict-free (swizzle source+read, keep
// the DMA dest linear).
// 1024 blocks x 512 threads (8 waves, 1 16-feature tile each).
// R3: M2 fragments gathered directly from M2w (prepack kernel removed);
// waves_per_eu back to (4,4) (best-known config; R2's min-only was neutral-
// to-negative).
// ---------------------------------------------------------------------------
__global__ __launch_bounds__(512) __attribute__((amdgpu_waves_per_eu(4, 4)))
void pool_partial(const float* __restrict__ z, const float* __restrict__ M2w,
                  float* __restrict__ part, unsigned short* __restrict__ zb,
                  int write_zb) {
    __shared__ __attribute__((aligned(16))) unsigned short zl[2][STRIP * ZSTR];

    const int tid  = threadIdx.x;
    const int w    = tid >> 6, lane = tid & 63, q = lane >> 4, l16 = lane & 15;
    const int blk  = blockIdx.x;
    const int b    = blk >> 5, ch = blk & (CH - 1);
    const long tok0 = (long)b * KK + (long)ch * TPB;

    // staging: thread covers token row sr (0..31), 8-elem group sg (0..15)
    const int sr = tid >> 4, sg = tid & 15;
    const int sgs = (sg ^ (sr & 7)) * 8;      // swizzled zb column (ushorts)

    // resident M2 tile fragments (wave w -> features w*16..w*16+15): 16 VGPR
    bf16x8 wf[4];
    for (int k = 0; k < 4; ++k)
        wf[k] = gather_frag(M2w, EE, w, k, l16, q);

    // stage strip 0
    {
        const float* r = z + (tok0 + sr) * EE + sg * 8;
        const bf16x8 c = cvt8(((const float4*)r)[0], ((const float4*)r)[1]);
        *(bf16x8*)&zl[0][sr * ZSTR + sg * 8] = c;
        if (write_zb) *(bf16x8*)(zb + (tok0 + sr) * EE + sgs) = c;
    }
    __syncthreads();

    f32x4 rmax[2];
    for (int t = 0; t < 2; ++t)
        for (int r = 0; r < 4; ++r) rmax[t][r] = -3.0e38f;

    for (int s = 0; s < NSTRIP; ++s) {
        const int p = s & 1;
        const bool pf = (s + 1 < NSTRIP);
        float4 A0, A1;
        if (pf) {
            const float* r = z + (tok0 + (s + 1) * STRIP + sr) * EE + sg * 8;
            A0 = ((const float4*)r)[0]; A1 = ((const float4*)r)[1];
        }

        for (int ts = 0; ts < 2; ++ts) {
            bf16x8 zf[4];
            for (int k = 0; k < 4; ++k)
                zf[k] = *(const bf16x8*)&zl[p][(ts * 16 + l16) * ZSTR + k * 32 + q * 8];
            f32x4 acc = {0.f, 0.f, 0.f, 0.f};
            for (int k = 0; k < 4; ++k)
                acc = __builtin_amdgcn_mfma_f32_16x16x32_bf16(wf[k], zf[k], acc, 0, 0, 0);
            for (int r = 0; r < 4; ++r)
                rmax[ts][r] = fmaxf(rmax[ts][r], acc[r]);
        }

        if (pf) {
            const bf16x8 c = cvt8(A0, A1);
            *(bf16x8*)&zl[1 - p][sr * ZSTR + sg * 8] = c;
            if (write_zb) *(bf16x8*)(zb + (tok0 + (s + 1) * STRIP + sr) * EE + sgs) = c;
        }
        __syncthreads();   // zl[1-p] ready; all reads of zl[p] done
    }

    f32x4 rm;
    for (int r = 0; r < 4; ++r) rm[r] = fmaxf(rmax[0][r], rmax[1][r]);
    for (int off = 1; off < 16; off <<= 1)
        for (int r = 0; r < 4; ++r)
            rm[r] = fmaxf(rm[r], __shfl_xor(rm[r], off, 64));
    if (l16 == 0) {
        float4 o; o.x = rm[0]; o.y = rm[1]; o.z = rm[2]; o.w = rm[3];
        *(float4*)(part + (size_t)blk * EE + w * 16 + q * 4) = o;
    }
}

// ---------------------------------------------------------------------------
// Kernel 2: out = relu([z | relu(z@M1^T + b1 + pooled)] @ U^T + bU)
// 1024 blocks x 512 threads (8 waves, 1 16-h tile each).
// R3 merges the former pool_reduce into a pre-phase here (and gathers M1/U
// fragments directly from fp32 weights, prepack removed):
//   pre:  pooled[b, w*16+q*4..+3] = max over CH chunks of part + M2b.
//         Lanes split the chunk axis (l16 -> 2 chunks each, 2 float4 loads =
//         exactly one 16 KB part[b] read per block), then width-16
//         __shfl_xor max-reduce. Bit-identical values to the old kernel.
// Main loop unchanged from R1 (best known):
//   top:  issue stage(s+1) -> zs[1-p]               (async DMA, 1 instr/wave)
//   ph1:  ds_read zf from zs[p] (XOR-deswizzled) -> M1 + U-low -> write ml[p]
//   BARRIER (compiler's vmcnt(0) drain completes stage(s+1) here)
//   ph2:  mf from ml[p] -> U-high -> float4 out stores.
// Buffer safety: as R1 (stage(s+1) targets the buffer whose last reads
// completed before the previous barrier; mid-strip barrier's vmcnt(0) drain
// covers stage(s) before its ph1 reads).
// ---------------------------------------------------------------------------
__global__ __launch_bounds__(512) __attribute__((amdgpu_waves_per_eu(4)))
void fused_main(const float* __restrict__ z, const unsigned short* __restrict__ zb,
                int use_zb,
                const float* __restrict__ M1w, const float* __restrict__ Uw,
                const float* __restrict__ M1b, const float* __restrict__ M2b,
                const float* __restrict__ Ub,
                const float* __restrict__ part, float* __restrict__ out) {
    __shared__ __attribute__((aligned(16))) unsigned short zs[2][STRIP * EE];   // 2 x 8 KB
    __shared__ __attribute__((aligned(16))) unsigned short ml[2][STRIP * ZSTR]; // 2 x 8.5 KB

    const int tid  = threadIdx.x;
    const int w    = tid >> 6, lane = tid & 63, q = lane >> 4, l16 = lane & 15;
    const int blk  = blockIdx.x;
    const int b    = blk >> 5, ch = blk & (CH - 1);
    const long tok0 = (long)b * KK + (long)ch * TPB;

    // issue strip-0 DMA first so its HBM/L3 latency overlaps the weight
    // gathers and the pool pre-phase below
    if (use_zb)
        gload_lds16(zb + tok0 * EE + tid * 8, &zs[0][w * 512]);

    // resident weights: M1 tile (16 VGPR) + U tile over K=256 (32 VGPR),
    // gathered directly from fp32 row-major (bit-identical to prepack)
    bf16x8 wf1[4];
    for (int k = 0; k < 4; ++k)
        wf1[k] = gather_frag(M1w, EE, w, k, l16, q);
    bf16x8 wfu[8];
    for (int kk = 0; kk < 8; ++kk)
        wfu[kk] = gather_frag(Uw, 2 * EE, w, kk, l16, q);

    // pre-phase: pooled = max_ch part[b,ch,f] + M2b[f], f = w*16+q*4..+3
    float4 pl;
    {
        const float* p0 = part + (size_t)(b * CH + l16 * 2) * EE + w * 16 + q * 4;
        const float4 v0 = ((const float4*)p0)[0];
        const float4 v1 = *(const float4*)(p0 + EE);
        pl.x = fmaxf(v0.x, v1.x); pl.y = fmaxf(v0.y, v1.y);
        pl.z = fmaxf(v0.z, v1.z); pl.w = fmaxf(v0.w, v1.w);
        for (int off = 1; off < 16; off <<= 1) {
            pl.x = fmaxf(pl.x, __shfl_xor(pl.x, off, 64));
            pl.y = fmaxf(pl.y, __shfl_xor(pl.y, off, 64));
            pl.z = fmaxf(pl.z, __shfl_xor(pl.z, off, 64));
            pl.w = fmaxf(pl.w, __shfl_xor(pl.w, off, 64));
        }
        const float4 m2 = *(const float4*)(M2b + w * 16 + q * 4);
        pl.x += m2.x; pl.y += m2.y; pl.z += m2.z; pl.w += m2.w;
    }

    const float4 mb = *(const float4*)(M1b + w * 16 + q * 4);
    float4 bp; bp.x = mb.x + pl.x; bp.y = mb.y + pl.y;
               bp.z = mb.z + pl.z; bp.w = mb.w + pl.w;
    const float4 ub = *(const float4*)(Ub + w * 16 + q * 4);

    if (use_zb)
        asm volatile("s_waitcnt vmcnt(0)" ::: "memory");
    __syncthreads();

    for (int s = 0; s < NSTRIP; ++s) {
        const int p = s & 1;
        const long trow = tok0 + s * STRIP;

        bf16x8 zf[2][4];
        if (use_zb) {
            // issue next-strip DMA before touching this strip's data
            if (s + 1 < NSTRIP)
                gload_lds16(zb + (trow + STRIP) * EE + tid * 8, &zs[1 - p][w * 512]);
            // ph1 fragment reads, de-swizzled: byte ^= ((row&7)<<4).
            // b128 bank groups g = ((k*4+q) ^ (row&7)) & 7 -> 8 lanes/group,
            // conflict-free floor.
            for (int ts = 0; ts < 2; ++ts) {
                const int row = ts * 16 + l16;
                const int sx  = (row & 7) << 4;
                const char* zrow = (const char*)&zs[p][row * EE];
                for (int k = 0; k < 4; ++k)
                    zf[ts][k] = *(const bf16x8*)(zrow + ((k * 64 + q * 16) ^ sx));
            }
        } else {
            for (int ts = 0; ts < 2; ++ts)
                for (int k = 0; k < 4; ++k) {
                    const float* r = z + (trow + ts * 16 + l16) * EE + k * 32 + q * 8;
                    zf[ts][k] = cvt8(((const float4*)r)[0], ((const float4*)r)[1]);
                }
        }

        f32x4 accU[2] = {};
        for (int ts = 0; ts < 2; ++ts) {
            f32x4 a1 = {0.f, 0.f, 0.f, 0.f};
            for (int k = 0; k < 4; ++k) {
                a1       = __builtin_amdgcn_mfma_f32_16x16x32_bf16(wf1[k], zf[ts][k], a1, 0, 0, 0);
                accU[ts] = __builtin_amdgcn_mfma_f32_16x16x32_bf16(wfu[k], zf[ts][k], accU[ts], 0, 0, 0);
            }
            ushort4 o;
            o.x = f2bf(fmaxf(a1[0] + bp.x, 0.f));
            o.y = f2bf(fmaxf(a1[1] + bp.y, 0.f));
            o.z = f2bf(fmaxf(a1[2] + bp.z, 0.f));
            o.w = f2bf(fmaxf(a1[3] + bp.w, 0.f));
            *(ushort4*)&ml[p][(ts * 16 + l16) * ZSTR + w * 16 + q * 4] = o;
        }
        __syncthreads();   // ml[p] complete; stage(s+1) drained (vmcnt(0))

        // ph2: U-high from ml[p], store out
        for (int ts = 0; ts < 2; ++ts) {
            bf16x8 mf[4];
            for (int k = 0; k < 4; ++k)
                mf[k] = *(const bf16x8*)&ml[p][(ts * 16 + l16) * ZSTR + k * 32 + q * 8];
            for (int k = 0; k < 4; ++k)
                accU[ts] = __builtin_amdgcn_mfma_f32_16x16x32_bf16(wfu[4 + k], mf[k], accU[ts], 0, 0, 0);
            float4 o;
            o.x = fmaxf(accU[ts][0] + ub.x, 0.f);
            o.y = fmaxf(accU[ts][1] + ub.y, 0.f);
            o.z = fmaxf(accU[ts][2] + ub.z, 0.f);
            o.w = fmaxf(accU[ts][3] + ub.w, 0.f);
            *(float4*)(out + (trow + ts * 16 + l16) * HH + w * 16 + q * 4) = o;
        }
    }
}

// ---------------------------------------------------------------------------
extern "C" void kernel_launch(void* const* d_in, const int* in_sizes, int n_in,
                              void* d_out, int out_size, void* d_ws, size_t ws_size,
                              hipStream_t stream) {
    const float* z   = (const float*)d_in[0];
    const float* M1w = (const float*)d_in[1];
    const float* M1b = (const float*)d_in[2];
    const float* M2w = (const float*)d_in[3];
    const float* M2b = (const float*)d_in[4];
    const float* Uw  = (const float*)d_in[5];
    const float* Ub  = (const float*)d_in[6];
    float* out = (float*)d_out;

    // ws: part 512K | zb 64M (opt)
    float* part = (float*)d_ws;
    unsigned short* zb = (unsigned short*)(part + (size_t)BB * CH * EE);
    const size_t head = (size_t)BB * CH * EE * 4;
    const int use_zb = (ws_size >= head + (size_t)BB * KK * EE * 2) ? 1 : 0;

    hipLaunchKernelGGL(pool_partial, dim3(BB * CH), dim3(512), 0, stream,
                       z, M2w, part, zb, use_zb);
    hipLaunchKernelGGL(fused_main,   dim3(BB * CH), dim3(512), 0, stream,
                       z, zb, use_zb, M1w, Uw, M1b, M2b, Ub, part, out);
}

// Round 4
// 276.232 us; speedup vs baseline: 1.1320x; 1.1320x over previous
//
#include <hip/hip_runtime.h>

// Problem constants (fixed by the reference).
#define BB 32
#define KK 8192
#define EE 128
#define HH 128
#define CH 32                     // chunks per batch -> 1024 blocks
#define TPB (KK / CH)             // 256 tokens per block
#define STRIP 32                  // tokens per LDS strip
#define NSTRIP (TPB / STRIP)      // 8
#define ZSTR 136                  // ml LDS row stride in shorts (272 B)

typedef short bf16x8 __attribute__((ext_vector_type(8)));
typedef float f32x4  __attribute__((ext_vector_type(4)));

static __device__ __forceinline__ unsigned short f2bf(float x) {
    union { float f; unsigned u; } v; v.f = x;
    unsigned u = v.u;
    u += 0x7FFFu + ((u >> 16) & 1u);   // RNE
    return (unsigned short)(u >> 16);
}

static __device__ __forceinline__ bf16x8 cvt8(float4 a, float4 b) {
    bf16x8 r;
    r[0] = (short)f2bf(a.x); r[1] = (short)f2bf(a.y);
    r[2] = (short)f2bf(a.z); r[3] = (short)f2bf(a.w);
    r[4] = (short)f2bf(b.x); r[5] = (short)f2bf(b.y);
    r[6] = (short)f2bf(b.z); r[7] = (short)f2bf(b.w);
    return r;
}

// Async global->LDS, 16 B per lane. LDS dest = wave-uniform base + lane*16.
typedef __attribute__((address_space(1))) void as1_void;
typedef __attribute__((address_space(3))) void as3_void;
static __device__ __forceinline__ void gload_lds16(const void* g, void* l) {
    __builtin_amdgcn_global_load_lds((as1_void*)g, (as3_void*)l, 16, 0, 0);
}

// ---------------------------------------------------------------------------
// Prologue: pack M1/M2/U fp32 row-major weights into bf16 MFMA A-fragments,
// fragment-linear: frag(tile,k) occupies 64 lanes x 16 B, lane-contiguous.
// Element for lane (q=lane>>4, l16=lane&15): row = tile*16+l16, col = k*32+q*8.
// 8192 threads total (32 blocks x 256).
// RESTORED in R4: R3's direct fp32 gathers forced the fused-loop weight
// fragments (48 VGPR) to be non-rematerializable -> ~70 MB/iter symmetric
// scratch-spill traffic and fused_main 45->95 us. Prepacked bf16 lets the
// compiler re-load fragments from L2 with one dwordx4 each, keeping VGPR=60.
// ---------------------------------------------------------------------------
__global__ void prepack(const float* __restrict__ M1w, const float* __restrict__ M2w,
                        const float* __restrict__ Uw,
                        unsigned short* __restrict__ w1p,
                        unsigned short* __restrict__ w2p,
                        unsigned short* __restrict__ wup) {
    const int id   = blockIdx.x * 256 + threadIdx.x;   // 0..8191
    const int lane = id & 63, fid = id >> 6;
    const int q = lane >> 4, l16 = lane & 15;
    const float* src;
    unsigned short* dst;
    if (fid < 32) {               // M1: tile=fid>>2, k=fid&3
        src = M1w + ((fid >> 2) * 16 + l16) * EE + (fid & 3) * 32 + q * 8;
        dst = w1p + (size_t)(fid * 64 + lane) * 8;
    } else if (fid < 64) {        // M2
        const int f = fid - 32;
        src = M2w + ((f >> 2) * 16 + l16) * EE + (f & 3) * 32 + q * 8;
        dst = w2p + (size_t)(f * 64 + lane) * 8;
    } else {                      // U: tile=(fid-64)>>3, kk=(fid-64)&7, 256 cols
        const int f = fid - 64;
        src = Uw + ((f >> 3) * 16 + l16) * (2 * EE) + (f & 7) * 32 + q * 8;
        dst = wup + (size_t)(f * 64 + lane) * 8;
    }
    *(bf16x8*)dst = cvt8(((const float4*)src)[0], ((const float4*)src)[1]);
}

// ---------------------------------------------------------------------------
// Kernel: partial column-max of z @ M2^T; emits z as bf16 (zb) if ws allows.
// zb is stored XOR-SWIZZLED within each 256-B token row:
//   byte_in_row ^= ((token & 7) << 4)
// so that fused_main can stage it LINEARLY via global_load_lds and read
// MFMA B-fragments from LDS bank-conflict-free (swizzle source+read, keep
// the DMA dest linear).
// 1024 blocks x 512 threads (8 waves, 1 16-feature tile each).
// Config: (4,4) waves_per_eu — best known (R2's min-only was neutral-to-neg).
// ---------------------------------------------------------------------------
__global__ __launch_bounds__(512) __attribute__((amdgpu_waves_per_eu(4, 4)))
void pool_partial(const float* __restrict__ z, const unsigned short* __restrict__ w2p,
                  float* __restrict__ part, unsigned short* __restrict__ zb,
                  int write_zb) {
    __shared__ __attribute__((aligned(16))) unsigned short zl[2][STRIP * ZSTR];

    const int tid  = threadIdx.x;
    const int w    = tid >> 6, lane = tid & 63, q = lane >> 4, l16 = lane & 15;
    const int blk  = blockIdx.x;
    const int b    = blk >> 5, ch = blk & (CH - 1);
    const long tok0 = (long)b * KK + (long)ch * TPB;

    // staging: thread covers token row sr (0..31), 8-elem group sg (0..15)
    const int sr = tid >> 4, sg = tid & 15;
    const int sgs = (sg ^ (sr & 7)) * 8;      // swizzled zb column (ushorts)

    // resident M2 tile fragments (wave w -> features w*16..w*16+15): 16 VGPR
    bf16x8 wf[4];
    for (int k = 0; k < 4; ++k)
        wf[k] = *(const bf16x8*)(w2p + (size_t)((w * 4 + k) * 64 + lane) * 8);

    // stage strip 0
    {
        const float* r = z + (tok0 + sr) * EE + sg * 8;
        const bf16x8 c = cvt8(((const float4*)r)[0], ((const float4*)r)[1]);
        *(bf16x8*)&zl[0][sr * ZSTR + sg * 8] = c;
        if (write_zb) *(bf16x8*)(zb + (tok0 + sr) * EE + sgs) = c;
    }
    __syncthreads();

    f32x4 rmax[2];
    for (int t = 0; t < 2; ++t)
        for (int r = 0; r < 4; ++r) rmax[t][r] = -3.0e38f;

    for (int s = 0; s < NSTRIP; ++s) {
        const int p = s & 1;
        const bool pf = (s + 1 < NSTRIP);
        float4 A0, A1;
        if (pf) {
            const float* r = z + (tok0 + (s + 1) * STRIP + sr) * EE + sg * 8;
            A0 = ((const float4*)r)[0]; A1 = ((const float4*)r)[1];
        }

        for (int ts = 0; ts < 2; ++ts) {
            bf16x8 zf[4];
            for (int k = 0; k < 4; ++k)
                zf[k] = *(const bf16x8*)&zl[p][(ts * 16 + l16) * ZSTR + k * 32 + q * 8];
            f32x4 acc = {0.f, 0.f, 0.f, 0.f};
            for (int k = 0; k < 4; ++k)
                acc = __builtin_amdgcn_mfma_f32_16x16x32_bf16(wf[k], zf[k], acc, 0, 0, 0);
            for (int r = 0; r < 4; ++r)
                rmax[ts][r] = fmaxf(rmax[ts][r], acc[r]);
        }

        if (pf) {
            const bf16x8 c = cvt8(A0, A1);
            *(bf16x8*)&zl[1 - p][sr * ZSTR + sg * 8] = c;
            if (write_zb) *(bf16x8*)(zb + (tok0 + (s + 1) * STRIP + sr) * EE + sgs) = c;
        }
        __syncthreads();   // zl[1-p] ready; all reads of zl[p] done
    }

    f32x4 rm;
    for (int r = 0; r < 4; ++r) rm[r] = fmaxf(rmax[0][r], rmax[1][r]);
    for (int off = 1; off < 16; off <<= 1)
        for (int r = 0; r < 4; ++r)
            rm[r] = fmaxf(rm[r], __shfl_xor(rm[r], off, 64));
    if (l16 == 0) {
        float4 o; o.x = rm[0]; o.y = rm[1]; o.z = rm[2]; o.w = rm[3];
        *(float4*)(part + (size_t)blk * EE + w * 16 + q * 4) = o;
    }
}

// ---------------------------------------------------------------------------
// Kernel: out = relu([z | relu(z@M1^T + b1 + pooled)] @ U^T + bU)
// 1024 blocks x 512 threads (8 waves, 1 16-h tile each).
// R4 = R1 main loop (best known, prepacked weights, VGPR~60 via remat) +
// the pool_reduce fold as a pre-phase (kept from R3; registers die pre-loop):
//   pre:  pooled[b, w*16+q*4..+3] = max over CH chunks of part + M2b.
//         Lanes split the chunk axis (l16 -> 2 chunks, 2 float4 loads =
//         exactly one 16 KB part[b] read per block), width-16 __shfl_xor
//         max-reduce. Bit-identical values to the old pool_reduce kernel.
// Main loop (unchanged from R1):
//   top:  issue stage(s+1) -> zs[1-p]               (async DMA, 1 instr/wave)
//   ph1:  ds_read zf from zs[p] (XOR-deswizzled) -> M1 + U-low -> write ml[p]
//   BARRIER (compiler's vmcnt(0) drain completes stage(s+1) here)
//   ph2:  mf from ml[p] -> U-high -> float4 out stores.
// Buffer safety: stage(s+1) targets the buffer whose last reads completed
// before the previous barrier; the mid-strip barrier's vmcnt(0) drain covers
// stage(s) before its ph1 reads.
// ---------------------------------------------------------------------------
__global__ __launch_bounds__(512) __attribute__((amdgpu_waves_per_eu(4)))
void fused_main(const float* __restrict__ z, const unsigned short* __restrict__ zb,
                int use_zb,
                const unsigned short* __restrict__ w1p,
                const unsigned short* __restrict__ wup,
                const float* __restrict__ M1b, const float* __restrict__ M2b,
                const float* __restrict__ Ub,
                const float* __restrict__ part, float* __restrict__ out) {
    __shared__ __attribute__((aligned(16))) unsigned short zs[2][STRIP * EE];   // 2 x 8 KB
    __shared__ __attribute__((aligned(16))) unsigned short ml[2][STRIP * ZSTR]; // 2 x 8.5 KB

    const int tid  = threadIdx.x;
    const int w    = tid >> 6, lane = tid & 63, q = lane >> 4, l16 = lane & 15;
    const int blk  = blockIdx.x;
    const int b    = blk >> 5, ch = blk & (CH - 1);
    const long tok0 = (long)b * KK + (long)ch * TPB;

    // issue strip-0 DMA first so its HBM/L3 latency overlaps the weight
    // loads and the pool pre-phase below
    if (use_zb)
        gload_lds16(zb + tok0 * EE + tid * 8, &zs[0][w * 512]);

    // resident weights: M1 tile (16 VGPR) + U tile over K=256 (32 VGPR),
    // from prepacked bf16 (lane-contiguous dwordx4, L2-resident, remat-able)
    bf16x8 wf1[4];
    for (int k = 0; k < 4; ++k)
        wf1[k] = *(const bf16x8*)(w1p + (size_t)((w * 4 + k) * 64 + lane) * 8);
    bf16x8 wfu[8];
    for (int kk = 0; kk < 8; ++kk)
        wfu[kk] = *(const bf16x8*)(wup + (size_t)((w * 8 + kk) * 64 + lane) * 8);

    // pre-phase: pooled = max_ch part[b,ch,f] + M2b[f], f = w*16+q*4..+3
    float4 pl;
    {
        const float* p0 = part + (size_t)(b * CH + l16 * 2) * EE + w * 16 + q * 4;
        const float4 v0 = ((const float4*)p0)[0];
        const float4 v1 = *(const float4*)(p0 + EE);
        pl.x = fmaxf(v0.x, v1.x); pl.y = fmaxf(v0.y, v1.y);
        pl.z = fmaxf(v0.z, v1.z); pl.w = fmaxf(v0.w, v1.w);
        for (int off = 1; off < 16; off <<= 1) {
            pl.x = fmaxf(pl.x, __shfl_xor(pl.x, off, 64));
            pl.y = fmaxf(pl.y, __shfl_xor(pl.y, off, 64));
            pl.z = fmaxf(pl.z, __shfl_xor(pl.z, off, 64));
            pl.w = fmaxf(pl.w, __shfl_xor(pl.w, off, 64));
        }
        const float4 m2 = *(const float4*)(M2b + w * 16 + q * 4);
        pl.x += m2.x; pl.y += m2.y; pl.z += m2.z; pl.w += m2.w;
    }

    const float4 mb = *(const float4*)(M1b + w * 16 + q * 4);
    float4 bp; bp.x = mb.x + pl.x; bp.y = mb.y + pl.y;
               bp.z = mb.z + pl.z; bp.w = mb.w + pl.w;
    const float4 ub = *(const float4*)(Ub + w * 16 + q * 4);

    if (use_zb)
        asm volatile("s_waitcnt vmcnt(0)" ::: "memory");
    __syncthreads();

    for (int s = 0; s < NSTRIP; ++s) {
        const int p = s & 1;
        const long trow = tok0 + s * STRIP;

        bf16x8 zf[2][4];
        if (use_zb) {
            // issue next-strip DMA before touching this strip's data
            if (s + 1 < NSTRIP)
                gload_lds16(zb + (trow + STRIP) * EE + tid * 8, &zs[1 - p][w * 512]);
            // ph1 fragment reads, de-swizzled: byte ^= ((row&7)<<4).
            // b128 bank groups g = ((k*4+q) ^ (row&7)) & 7 -> 8 lanes/group,
            // conflict-free floor.
            for (int ts = 0; ts < 2; ++ts) {
                const int row = ts * 16 + l16;
                const int sx  = (row & 7) << 4;
                const char* zrow = (const char*)&zs[p][row * EE];
                for (int k = 0; k < 4; ++k)
                    zf[ts][k] = *(const bf16x8*)(zrow + ((k * 64 + q * 16) ^ sx));
            }
        } else {
            for (int ts = 0; ts < 2; ++ts)
                for (int k = 0; k < 4; ++k) {
                    const float* r = z + (trow + ts * 16 + l16) * EE + k * 32 + q * 8;
                    zf[ts][k] = cvt8(((const float4*)r)[0], ((const float4*)r)[1]);
                }
        }

        f32x4 accU[2] = {};
        for (int ts = 0; ts < 2; ++ts) {
            f32x4 a1 = {0.f, 0.f, 0.f, 0.f};
            for (int k = 0; k < 4; ++k) {
                a1       = __builtin_amdgcn_mfma_f32_16x16x32_bf16(wf1[k], zf[ts][k], a1, 0, 0, 0);
                accU[ts] = __builtin_amdgcn_mfma_f32_16x16x32_bf16(wfu[k], zf[ts][k], accU[ts], 0, 0, 0);
            }
            ushort4 o;
            o.x = f2bf(fmaxf(a1[0] + bp.x, 0.f));
            o.y = f2bf(fmaxf(a1[1] + bp.y, 0.f));
            o.z = f2bf(fmaxf(a1[2] + bp.z, 0.f));
            o.w = f2bf(fmaxf(a1[3] + bp.w, 0.f));
            *(ushort4*)&ml[p][(ts * 16 + l16) * ZSTR + w * 16 + q * 4] = o;
        }
        __syncthreads();   // ml[p] complete; stage(s+1) drained (vmcnt(0))

        // ph2: U-high from ml[p], store out
        for (int ts = 0; ts < 2; ++ts) {
            bf16x8 mf[4];
            for (int k = 0; k < 4; ++k)
                mf[k] = *(const bf16x8*)&ml[p][(ts * 16 + l16) * ZSTR + k * 32 + q * 8];
            for (int k = 0; k < 4; ++k)
                accU[ts] = __builtin_amdgcn_mfma_f32_16x16x32_bf16(wfu[4 + k], mf[k], accU[ts], 0, 0, 0);
            float4 o;
            o.x = fmaxf(accU[ts][0] + ub.x, 0.f);
            o.y = fmaxf(accU[ts][1] + ub.y, 0.f);
            o.z = fmaxf(accU[ts][2] + ub.z, 0.f);
            o.w = fmaxf(accU[ts][3] + ub.w, 0.f);
            *(float4*)(out + (trow + ts * 16 + l16) * HH + w * 16 + q * 4) = o;
        }
    }
}

// ---------------------------------------------------------------------------
extern "C" void kernel_launch(void* const* d_in, const int* in_sizes, int n_in,
                              void* d_out, int out_size, void* d_ws, size_t ws_size,
                              hipStream_t stream) {
    const float* z   = (const float*)d_in[0];
    const float* M1w = (const float*)d_in[1];
    const float* M1b = (const float*)d_in[2];
    const float* M2w = (const float*)d_in[3];
    const float* M2b = (const float*)d_in[4];
    const float* Uw  = (const float*)d_in[5];
    const float* Ub  = (const float*)d_in[6];
    float* out = (float*)d_out;

    // ws: w1p 32K | w2p 32K | wup 64K | part 512K | zb 64M (opt)
    unsigned short* w1p = (unsigned short*)d_ws;
    unsigned short* w2p = w1p + 16384;
    unsigned short* wup = w2p + 16384;
    float* part = (float*)(wup + 32768);
    unsigned short* zb = (unsigned short*)(part + (size_t)BB * CH * EE);
    const size_t head = 2 * 16384 * 2 + 32768 * 2 + (size_t)BB * CH * EE * 4;
    const int use_zb = (ws_size >= head + (size_t)BB * KK * EE * 2) ? 1 : 0;

    hipLaunchKernelGGL(prepack,      dim3(32),      dim3(256), 0, stream,
                       M1w, M2w, Uw, w1p, w2p, wup);
    hipLaunchKernelGGL(pool_partial, dim3(BB * CH), dim3(512), 0, stream,
                       z, w2p, part, zb, use_zb);
    hipLaunchKernelGGL(fused_main,   dim3(BB * CH), dim3(512), 0, stream,
                       z, zb, use_zb, w1p, wup, M1b, M2b, Ub, part, out);
}

// Round 5
// 275.777 us; speedup vs baseline: 1.1339x; 1.0016x over previous
//
#include <hip/hip_runtime.h>

// Problem constants (fixed by the reference).
#define BB 32
#define KK 8192
#define EE 128
#define HH 128
#define CH 32                     // chunks per batch -> 1024 blocks
#define TPB (KK / CH)             // 256 tokens per block
#define STRIP 32                  // tokens per LDS strip
#define NSTRIP (TPB / STRIP)      // 8
#define ZSTR 136                  // ml LDS row stride in shorts (272 B)

typedef short bf16x8 __attribute__((ext_vector_type(8)));
typedef float f32x4  __attribute__((ext_vector_type(4)));

static __device__ __forceinline__ unsigned short f2bf(float x) {
    union { float f; unsigned u; } v; v.f = x;
    unsigned u = v.u;
    u += 0x7FFFu + ((u >> 16) & 1u);   // RNE
    return (unsigned short)(u >> 16);
}

static __device__ __forceinline__ bf16x8 cvt8(float4 a, float4 b) {
    bf16x8 r;
    r[0] = (short)f2bf(a.x); r[1] = (short)f2bf(a.y);
    r[2] = (short)f2bf(a.z); r[3] = (short)f2bf(a.w);
    r[4] = (short)f2bf(b.x); r[5] = (short)f2bf(b.y);
    r[6] = (short)f2bf(b.z); r[7] = (short)f2bf(b.w);
    return r;
}

// Async global->LDS, 16 B per lane. LDS dest = wave-uniform base + lane*16.
typedef __attribute__((address_space(1))) void as1_void;
typedef __attribute__((address_space(3))) void as3_void;
static __device__ __forceinline__ void gload_lds16(const void* g, void* l) {
    __builtin_amdgcn_global_load_lds((as1_void*)g, (as3_void*)l, 16, 0, 0);
}

// Raw barrier: writer-side lgkmcnt(0) (LDS writes visible) + s_barrier.
// Does NOT drain vmcnt — prefetch loads / DMAs / stores keep flying.
// sched_barrier(0) + "memory" clobbers pin ordering (guide rule #18).
#define WAVE_BARRIER_LGKM()                                         \
    do {                                                            \
        __builtin_amdgcn_sched_barrier(0);                          \
        asm volatile("s_waitcnt lgkmcnt(0)" ::: "memory");          \
        __builtin_amdgcn_sched_barrier(0);                          \
        __builtin_amdgcn_s_barrier();                               \
        asm volatile("" ::: "memory");                              \
        __builtin_amdgcn_sched_barrier(0);                          \
    } while (0)

// ---------------------------------------------------------------------------
// Prologue: pack M1/M2/U fp32 row-major weights into bf16 MFMA A-fragments,
// fragment-linear: frag(tile,k) occupies 64 lanes x 16 B, lane-contiguous.
// Element for lane (q=lane>>4, l16=lane&15): row = tile*16+l16, col = k*32+q*8.
// Keeping prepack is load-bearing: it lets the fused-loop weight fragments be
// REMATERIALIZED from L2 as single dwordx4 loads (VGPR stays ~60). R3 proved
// that direct fp32 gathers instead cause ~70 MB/strip scratch spills.
// ---------------------------------------------------------------------------
__global__ void prepack(const float* __restrict__ M1w, const float* __restrict__ M2w,
                        const float* __restrict__ Uw,
                        unsigned short* __restrict__ w1p,
                        unsigned short* __restrict__ w2p,
                        unsigned short* __restrict__ wup) {
    const int id   = blockIdx.x * 256 + threadIdx.x;   // 0..8191
    const int lane = id & 63, fid = id >> 6;
    const int q = lane >> 4, l16 = lane & 15;
    const float* src;
    unsigned short* dst;
    if (fid < 32) {               // M1: tile=fid>>2, k=fid&3
        src = M1w + ((fid >> 2) * 16 + l16) * EE + (fid & 3) * 32 + q * 8;
        dst = w1p + (size_t)(fid * 64 + lane) * 8;
    } else if (fid < 64) {        // M2
        const int f = fid - 32;
        src = M2w + ((f >> 2) * 16 + l16) * EE + (f & 3) * 32 + q * 8;
        dst = w2p + (size_t)(f * 64 + lane) * 8;
    } else {                      // U: tile=(fid-64)>>3, kk=(fid-64)&7, 256 cols
        const int f = fid - 64;
        src = Uw + ((f >> 3) * 16 + l16) * (2 * EE) + (f & 7) * 32 + q * 8;
        dst = wup + (size_t)(f * 64 + lane) * 8;
    }
    *(bf16x8*)dst = cvt8(((const float4*)src)[0], ((const float4*)src)[1]);
}

// ---------------------------------------------------------------------------
// Kernel: partial column-max of z @ M2^T; emits z as bf16 (zb) if ws allows.
// zb is stored XOR-SWIZZLED within each 256-B token row:
//   byte_in_row ^= ((token & 7) << 4)
// so fused_main can stage it LINEARLY via global_load_lds and ds_read
// conflict-free (swizzle source+read, keep the DMA dest linear).
//
// R5 pipeline change: raw lgkm-only barriers (no vmcnt drain) + 2-deep
// register prefetch. P[t&1] holds strip t's fp32 data; loads for s+2 are
// issued at the top of strip s and consumed (cvt->zl) at the END of s+1 —
// a ~2-strip window > ~900-cyc HBM latency. The compiler auto-inserts the
// precise vmcnt before the cvt (register loads = known dataflow). zb stores
// are never drained (nothing in this kernel reads zb).
// Race safety: zl[x] writers (end of s, ds_write) and cross-wave readers
// (MFMA of s+1) are separated by barrier(s) with writer-side lgkmcnt(0).
// Prefetch regs are thread-private. Unchanged: (4,4) waves_per_eu.
// ---------------------------------------------------------------------------
__global__ __launch_bounds__(512) __attribute__((amdgpu_waves_per_eu(4, 4)))
void pool_partial(const float* __restrict__ z, const unsigned short* __restrict__ w2p,
                  float* __restrict__ part, unsigned short* __restrict__ zb,
                  int write_zb) {
    __shared__ __attribute__((aligned(16))) unsigned short zl[2][STRIP * ZSTR];

    const int tid  = threadIdx.x;
    const int w    = tid >> 6, lane = tid & 63, q = lane >> 4, l16 = lane & 15;
    const int blk  = blockIdx.x;
    const int b    = blk >> 5, ch = blk & (CH - 1);
    const long tok0 = (long)b * KK + (long)ch * TPB;

    // staging: thread covers token row sr (0..31), 8-elem group sg (0..15)
    const int sr = tid >> 4, sg = tid & 15;
    const int sgs = (sg ^ (sr & 7)) * 8;      // swizzled zb column (ushorts)

    // resident M2 tile fragments (wave w -> features w*16..w*16+15): 16 VGPR
    bf16x8 wf[4];
    for (int k = 0; k < 4; ++k)
        wf[k] = *(const bf16x8*)(w2p + (size_t)((w * 4 + k) * 64 + lane) * 8);

    // P[t&1] = fp32 prefetch regs for strip t (indices static after unroll)
    float4 P[2][2];

    // prologue: stage strip 0 directly; issue strip-1 prefetch (kept in
    // flight across the barrier — raw barrier does not drain vmcnt)
    {
        const float* r0 = z + (tok0 + sr) * EE + sg * 8;
        const float4 a = ((const float4*)r0)[0], c4 = ((const float4*)r0)[1];
        const float* r1 = z + (tok0 + STRIP + sr) * EE + sg * 8;
        P[1][0] = ((const float4*)r1)[0];
        P[1][1] = ((const float4*)r1)[1];
        const bf16x8 c = cvt8(a, c4);
        *(bf16x8*)&zl[0][sr * ZSTR + sg * 8] = c;
        if (write_zb) *(bf16x8*)(zb + (tok0 + sr) * EE + sgs) = c;
    }
    WAVE_BARRIER_LGKM();

    f32x4 rmax[2];
    for (int t = 0; t < 2; ++t)
        for (int r = 0; r < 4; ++r) rmax[t][r] = -3.0e38f;

#pragma unroll
    for (int s = 0; s < NSTRIP; ++s) {
        const int p = s & 1;

        // issue prefetch for strip s+2 into P[(s+2)&1] = P[p]
        // (P[p]'s previous content, strip s, was consumed at end of s-1)
        if (s + 2 < NSTRIP) {
            const float* r = z + (tok0 + (s + 2) * STRIP + sr) * EE + sg * 8;
            P[p][0] = ((const float4*)r)[0];
            P[p][1] = ((const float4*)r)[1];
        }

        for (int ts = 0; ts < 2; ++ts) {
            bf16x8 zf[4];
            for (int k = 0; k < 4; ++k)
                zf[k] = *(const bf16x8*)&zl[p][(ts * 16 + l16) * ZSTR + k * 32 + q * 8];
            f32x4 acc = {0.f, 0.f, 0.f, 0.f};
            for (int k = 0; k < 4; ++k)
                acc = __builtin_amdgcn_mfma_f32_16x16x32_bf16(wf[k], zf[k], acc, 0, 0, 0);
            for (int r = 0; r < 4; ++r)
                rmax[ts][r] = fmaxf(rmax[ts][r], acc[r]);
        }

        // emit strip s+1 (data P[1-p], loaded at top of s-1): compiler
        // inserts the exact vmcnt before the cvt; the s+2 loads above and
        // older zb stores stay outstanding.
        if (s + 1 < NSTRIP) {
            const bf16x8 c = cvt8(P[1 - p][0], P[1 - p][1]);
            *(bf16x8*)&zl[1 - p][sr * ZSTR + sg * 8] = c;
            if (write_zb) *(bf16x8*)(zb + (tok0 + (s + 1) * STRIP + sr) * EE + sgs) = c;
            WAVE_BARRIER_LGKM();   // zl[1-p] visible; no vmcnt drain
        }
        // s == NSTRIP-1: nothing after this strip's MFMA needs a barrier
    }

    f32x4 rm;
    for (int r = 0; r < 4; ++r) rm[r] = fmaxf(rmax[0][r], rmax[1][r]);
    for (int off = 1; off < 16; off <<= 1)
        for (int r = 0; r < 4; ++r)
            rm[r] = fmaxf(rm[r], __shfl_xor(rm[r], off, 64));
    if (l16 == 0) {
        float4 o; o.x = rm[0]; o.y = rm[1]; o.z = rm[2]; o.w = rm[3];
        *(float4*)(part + (size_t)blk * EE + w * 16 + q * 4) = o;
    }
}

// ---------------------------------------------------------------------------
// Kernel: out = relu([z | relu(z@M1^T + b1 + pooled)] @ U^T + bU)
// 1024 blocks x 512 threads (8 waves, 1 16-h tile each).
//
// R5 pipeline: 3-buffer zs, DMA issued TWO strips ahead, counted vmcnt
// (writer-side, before the raw barrier) instead of __syncthreads' vmcnt(0)
// drain. Per strip s:
//   top:  issue gload(s+2) -> zs[(s+2)%3]
//   ph1:  zf ds_reads from zs[s%3] (XOR-deswizzled) -> M1 + U-low -> ml[s&1]
//   pre-barrier: vmcnt(N) gates THIS wave's gload(s+1) (issued at top of
//        s-1; its ~2-strip window covers HBM latency). N = #vmem ops issued
//        after gload(s+1): 2 out-stores (ph2 s-1) + gload(s+2) if issued
//        -> vmcnt(3) for s in 1..NSTRIP-3, vmcnt(2) at s=NSTRIP-2, none at
//        s=0 (g(1) drained in prologue) and s=NSTRIP-1 (nothing gated).
//        Compiler-inserted remat loads only inflate counts -> over-wait,
//        never under-wait (vmcnt retires oldest-first, m135).
//   then lgkmcnt(0) + s_barrier: ml[s&1] visible AND every wave has gated
//        its own zs[(s+1)%3] slice -> whole buffer valid for ph1(s+1).
//   ph2:  mf from ml[s&1] -> U-high -> float4 out stores (never drained).
// Buffer safety:
//   zs[(s+2)%3] DMA target: last read in ph1(s-1) (same index mod 3),
//     completed by all waves before barrier(s-1) < issue point.  ml[s&1]
//     rewrite in ph1(s+2): all ph2(s) reads complete before barrier(s+1).
// ---------------------------------------------------------------------------
__global__ __launch_bounds__(512) __attribute__((amdgpu_waves_per_eu(4)))
void fused_main(const float* __restrict__ z, const unsigned short* __restrict__ zb,
                int use_zb,
                const unsigned short* __restrict__ w1p,
                const unsigned short* __restrict__ wup,
                const float* __restrict__ M1b, const float* __restrict__ M2b,
                const float* __restrict__ Ub,
                const float* __restrict__ part, float* __restrict__ out) {
    __shared__ __attribute__((aligned(16))) unsigned short zs[3][STRIP * EE];   // 3 x 8 KB
    __shared__ __attribute__((aligned(16))) unsigned short ml[2][STRIP * ZSTR]; // 2 x 8.5 KB

    const int tid  = threadIdx.x;
    const int w    = tid >> 6, lane = tid & 63, q = lane >> 4, l16 = lane & 15;
    const int blk  = blockIdx.x;
    const int b    = blk >> 5, ch = blk & (CH - 1);
    const long tok0 = (long)b * KK + (long)ch * TPB;

    // issue strip-0/1 DMAs first: latency overlaps weight loads + pre-phase
    if (use_zb) {
        gload_lds16(zb + tok0 * EE + tid * 8, &zs[0][w * 512]);
        gload_lds16(zb + (tok0 + STRIP) * EE + tid * 8, &zs[1][w * 512]);
    }

    // resident weights: M1 tile (16 VGPR) + U tile over K=256 (32 VGPR),
    // from prepacked bf16 (lane-contiguous dwordx4, L2-resident, remat-able)
    bf16x8 wf1[4];
    for (int k = 0; k < 4; ++k)
        wf1[k] = *(const bf16x8*)(w1p + (size_t)((w * 4 + k) * 64 + lane) * 8);
    bf16x8 wfu[8];
    for (int kk = 0; kk < 8; ++kk)
        wfu[kk] = *(const bf16x8*)(wup + (size_t)((w * 8 + kk) * 64 + lane) * 8);

    // pre-phase: pooled = max_ch part[b,ch,f] + M2b[f], f = w*16+q*4..+3
    float4 pl;
    {
        const float* p0 = part + (size_t)(b * CH + l16 * 2) * EE + w * 16 + q * 4;
        const float4 v0 = ((const float4*)p0)[0];
        const float4 v1 = *(const float4*)(p0 + EE);
        pl.x = fmaxf(v0.x, v1.x); pl.y = fmaxf(v0.y, v1.y);
        pl.z = fmaxf(v0.z, v1.z); pl.w = fmaxf(v0.w, v1.w);
        for (int off = 1; off < 16; off <<= 1) {
            pl.x = fmaxf(pl.x, __shfl_xor(pl.x, off, 64));
            pl.y = fmaxf(pl.y, __shfl_xor(pl.y, off, 64));
            pl.z = fmaxf(pl.z, __shfl_xor(pl.z, off, 64));
            pl.w = fmaxf(pl.w, __shfl_xor(pl.w, off, 64));
        }
        const float4 m2 = *(const float4*)(M2b + w * 16 + q * 4);
        pl.x += m2.x; pl.y += m2.y; pl.z += m2.z; pl.w += m2.w;
    }

    const float4 mb = *(const float4*)(M1b + w * 16 + q * 4);
    float4 bp; bp.x = mb.x + pl.x; bp.y = mb.y + pl.y;
               bp.z = mb.z + pl.z; bp.w = mb.w + pl.w;
    const float4 ub = *(const float4*)(Ub + w * 16 + q * 4);

    // prologue drain: g(0), g(1) (and weight loads) all complete once
    if (use_zb)
        asm volatile("s_waitcnt vmcnt(0)" ::: "memory");
    __syncthreads();

#pragma unroll
    for (int s = 0; s < NSTRIP; ++s) {
        const int p  = s & 1;       // ml parity
        const int zi = s % 3;       // zs buffer for this strip
        const long trow = tok0 + s * STRIP;

        bf16x8 zf[2][4];
        if (use_zb) {
            // issue DMA two strips ahead
            if (s + 2 < NSTRIP)
                gload_lds16(zb + (trow + 2 * STRIP) * EE + tid * 8,
                            &zs[(s + 2) % 3][w * 512]);
            // ph1 fragment reads, de-swizzled: byte ^= ((row&7)<<4);
            // conflict-free (8 lanes per 4-bank group).
            for (int ts = 0; ts < 2; ++ts) {
                const int row = ts * 16 + l16;
                const int sx  = (row & 7) << 4;
                const char* zrow = (const char*)&zs[zi][row * EE];
                for (int k = 0; k < 4; ++k)
                    zf[ts][k] = *(const bf16x8*)(zrow + ((k * 64 + q * 16) ^ sx));
            }
        } else {
            for (int ts = 0; ts < 2; ++ts)
                for (int k = 0; k < 4; ++k) {
                    const float* r = z + (trow + ts * 16 + l16) * EE + k * 32 + q * 8;
                    zf[ts][k] = cvt8(((const float4*)r)[0], ((const float4*)r)[1]);
                }
        }

        f32x4 accU[2] = {};
        for (int ts = 0; ts < 2; ++ts) {
            f32x4 a1 = {0.f, 0.f, 0.f, 0.f};
            for (int k = 0; k < 4; ++k) {
                a1       = __builtin_amdgcn_mfma_f32_16x16x32_bf16(wf1[k], zf[ts][k], a1, 0, 0, 0);
                accU[ts] = __builtin_amdgcn_mfma_f32_16x16x32_bf16(wfu[k], zf[ts][k], accU[ts], 0, 0, 0);
            }
            ushort4 o;
            o.x = f2bf(fmaxf(a1[0] + bp.x, 0.f));
            o.y = f2bf(fmaxf(a1[1] + bp.y, 0.f));
            o.z = f2bf(fmaxf(a1[2] + bp.z, 0.f));
            o.w = f2bf(fmaxf(a1[3] + bp.w, 0.f));
            *(ushort4*)&ml[p][(ts * 16 + l16) * ZSTR + w * 16 + q * 4] = o;
        }

        // writer-side gate for gload(s+1), then lgkm-only barrier
        __builtin_amdgcn_sched_barrier(0);
        if (use_zb) {
            if (s >= 1 && s + 2 < NSTRIP) {
                asm volatile("s_waitcnt vmcnt(3)" ::: "memory");
            } else if (s >= 1 && s + 1 < NSTRIP) {
                asm volatile("s_waitcnt vmcnt(2)" ::: "memory");
            }
            // s==0: g(1) already drained in prologue; s==NSTRIP-1: nothing
            __builtin_amdgcn_sched_barrier(0);
        }
        WAVE_BARRIER_LGKM();   // ml[p] + all waves' zs[(s+1)%3] slices ready

        // ph2: U-high from ml[p], store out (stores never drained)
        for (int ts = 0; ts < 2; ++ts) {
            bf16x8 mf[4];
            for (int k = 0; k < 4; ++k)
                mf[k] = *(const bf16x8*)&ml[p][(ts * 16 + l16) * ZSTR + k * 32 + q * 8];
            for (int k = 0; k < 4; ++k)
                accU[ts] = __builtin_amdgcn_mfma_f32_16x16x32_bf16(wfu[4 + k], mf[k], accU[ts], 0, 0, 0);
            float4 o;
            o.x = fmaxf(accU[ts][0] + ub.x, 0.f);
            o.y = fmaxf(accU[ts][1] + ub.y, 0.f);
            o.z = fmaxf(accU[ts][2] + ub.z, 0.f);
            o.w = fmaxf(accU[ts][3] + ub.w, 0.f);
            *(float4*)(out + (trow + ts * 16 + l16) * HH + w * 16 + q * 4) = o;
        }
    }
}

// ---------------------------------------------------------------------------
extern "C" void kernel_launch(void* const* d_in, const int* in_sizes, int n_in,
                              void* d_out, int out_size, void* d_ws, size_t ws_size,
                              hipStream_t stream) {
    const float* z   = (const float*)d_in[0];
    const float* M1w = (const float*)d_in[1];
    const float* M1b = (const float*)d_in[2];
    const float* M2w = (const float*)d_in[3];
    const float* M2b = (const float*)d_in[4];
    const float* Uw  = (const float*)d_in[5];
    const float* Ub  = (const float*)d_in[6];
    float* out = (float*)d_out;

    // ws: w1p 32K | w2p 32K | wup 64K | part 512K | zb 64M (opt)
    unsigned short* w1p = (unsigned short*)d_ws;
    unsigned short* w2p = w1p + 16384;
    unsigned short* wup = w2p + 16384;
    float* part = (float*)(wup + 32768);
    unsigned short* zb = (unsigned short*)(part + (size_t)BB * CH * EE);
    const size_t head = 2 * 16384 * 2 + 32768 * 2 + (size_t)BB * CH * EE * 4;
    const int use_zb = (ws_size >= head + (size_t)BB * KK * EE * 2) ? 1 : 0;

    hipLaunchKernelGGL(prepack,      dim3(32),      dim3(256), 0, stream,
                       M1w, M2w, Uw, w1p, w2p, wup);
    hipLaunchKernelGGL(pool_partial, dim3(BB * CH), dim3(512), 0, stream,
                       z, w2p, part, zb, use_zb);
    hipLaunchKernelGGL(fused_main,   dim3(BB * CH), dim3(512), 0, stream,
                       z, zb, use_zb, w1p, wup, M1b, M2b, Ub, part, out);
}